// Round 5
// baseline (2144.734 us; speedup 1.0000x reference)
//
#include <hip/hip_runtime.h>
#include <math.h>

#define NN 50000
#define NE 800000

#define LRELU(v) ((v) > 0.f ? (v) : 0.2f * (v))

typedef __attribute__((ext_vector_type(4))) float f32x4;
typedef __attribute__((ext_vector_type(8))) short bf16x8;

static __device__ __forceinline__ unsigned short f2bf(float f) {
  union { float f; unsigned int i; } c; c.f = f;
  unsigned int r = c.i + 0x7fff + ((c.i >> 16) & 1);   // RNE
  return (unsigned short)(r >> 16);
}
static __device__ __forceinline__ float bflo(unsigned int u) {
  union { unsigned int i; float f; } c; c.i = u << 16; return c.f;
}
static __device__ __forceinline__ float bfhi(unsigned int u) {
  union { unsigned int i; float f; } c; c.i = u & 0xffff0000u; return c.f;
}

// ---------------------------------------------------------------------------
// GEMM: outb = bf16(A @ W + b). blockIdx.y picks (W0,b0)->outb0 / (W1,b1)->outb1.
// BM=64, BN=256, BK=32, 256 threads.
// ---------------------------------------------------------------------------
__global__ __launch_bounds__(256)
void gemm_bias2(const float* __restrict__ A,
                const float* __restrict__ W0, const float* __restrict__ b0,
                unsigned short* __restrict__ outb0,
                const float* __restrict__ W1, const float* __restrict__ b1,
                unsigned short* __restrict__ outb1,
                int N, int K) {
  const float* W    = blockIdx.y ? W1 : W0;
  const float* bias = blockIdx.y ? b1 : b0;
  unsigned short* outb = blockIdx.y ? outb1 : outb0;

  __shared__ float As[32][68];
  __shared__ float Bs[32][256];

  const int tid  = threadIdx.x;
  const int c4   = (tid & 63) * 4;
  const int rg   = tid >> 6;
  const int row0 = blockIdx.x * 64;

  float acc[16][4];
#pragma unroll
  for (int i = 0; i < 16; ++i)
#pragma unroll
    for (int j = 0; j < 4; ++j) acc[i][j] = 0.f;

  for (int k0 = 0; k0 < K; k0 += 32) {
#pragma unroll
    for (int p = 0; p < 2; ++p) {
      const int r  = p * 32 + (tid >> 3);
      const int kq = (tid & 7) * 4;
      float4 v = make_float4(0.f, 0.f, 0.f, 0.f);
      const int grow = row0 + r;
      if (grow < N) v = *(const float4*)(A + (size_t)grow * K + k0 + kq);
      As[kq + 0][r] = v.x; As[kq + 1][r] = v.y;
      As[kq + 2][r] = v.z; As[kq + 3][r] = v.w;
    }
#pragma unroll
    for (int p = 0; p < 8; ++p) {
      const int lin = p * 1024 + tid * 4;
      const int kk = lin >> 8, cc = lin & 255;
      *(float4*)&Bs[kk][cc] = *(const float4*)(W + (size_t)(k0 + kk) * 256 + cc);
    }
    __syncthreads();
#pragma unroll
    for (int kk = 0; kk < 32; ++kk) {
      const float4 b = *(const float4*)&Bs[kk][c4];
      const float bb[4] = {b.x, b.y, b.z, b.w};
#pragma unroll
      for (int q = 0; q < 4; ++q) {
        const float4 a = *(const float4*)&As[kk][rg * 16 + q * 4];
        const float aa[4] = {a.x, a.y, a.z, a.w};
#pragma unroll
        for (int m = 0; m < 4; ++m)
#pragma unroll
          for (int j = 0; j < 4; ++j) acc[q * 4 + m][j] += aa[m] * bb[j];
      }
    }
    __syncthreads();
  }

  const float4 bv = *(const float4*)(bias + c4);
#pragma unroll
  for (int i = 0; i < 16; ++i) {
    const int row = row0 + rg * 16 + i;
    if (row < N) {
      ushort4 ob;
      ob.x = f2bf(acc[i][0] + bv.x); ob.y = f2bf(acc[i][1] + bv.y);
      ob.z = f2bf(acc[i][2] + bv.z); ob.w = f2bf(acc[i][3] + bv.w);
      *(ushort4*)(outb + (size_t)row * 256 + c4) = ob;
    }
  }
}

// ---------------------------------------------------------------------------
// WeT prep: wet[c*64+k] = bf16(We[k*256+c]).
// ---------------------------------------------------------------------------
__global__ __launch_bounds__(256)
void conv_wet(const float* __restrict__ We1, unsigned short* __restrict__ wet1,
              const float* __restrict__ We2, unsigned short* __restrict__ wet2) {
  const float* We = blockIdx.y ? We2 : We1;
  unsigned short* wet = blockIdx.y ? wet2 : wet1;
  const int idx = blockIdx.x * 256 + threadIdx.x;
  const int k = idx >> 8, c = idx & 255;
  wet[c * 64 + k] = f2bf(We[(size_t)k * 256 + c]);
}

// ---------------------------------------------------------------------------
// CSR build: histogram -> exclusive scan -> bucket fill
// ---------------------------------------------------------------------------
__global__ __launch_bounds__(256)
void dst_hist(const int* __restrict__ dst, int* __restrict__ cnt) {
  const int e = blockIdx.x * 256 + threadIdx.x;
  if (e < NE) atomicAdd(&cnt[dst[e]], 1);
}

__global__ __launch_bounds__(1024)
void exscan(int* __restrict__ cnt, int* __restrict__ row_start,
            int* __restrict__ cur, int n) {
  __shared__ int buf[1024];
  __shared__ int carry;
  if (threadIdx.x == 0) carry = 0;
  __syncthreads();
  for (int base = 0; base < n; base += 1024) {
    const int i = base + threadIdx.x;
    const int v = (i < n) ? cnt[i] : 0;
    buf[threadIdx.x] = v;
    __syncthreads();
    for (int off = 1; off < 1024; off <<= 1) {
      const int t = (threadIdx.x >= off) ? buf[threadIdx.x - off] : 0;
      __syncthreads();
      buf[threadIdx.x] += t;
      __syncthreads();
    }
    const int excl = buf[threadIdx.x] - v + carry;
    if (i < n) { row_start[i] = excl; cur[i] = excl; }
    __syncthreads();
    if (threadIdx.x == 1023) carry += buf[1023];
    __syncthreads();
  }
  if (threadIdx.x == 0) row_start[n] = carry;
}

__global__ __launch_bounds__(256)
void bucket_fill(const int* __restrict__ dst, int* __restrict__ cur,
                 int* __restrict__ eid) {
  const int e = blockIdx.x * 256 + threadIdx.x;
  if (e < NE) {
    const int p = atomicAdd(&cur[dst[e]], 1);
    eid[p] = e;
  }
}

// ---------------------------------------------------------------------------
// Fused GATv2 edge+softmax+aggregate. One wave per dst node, 4 waves/block.
// Per 16-edge chunk (CSR):
//   ee^T via mfma(A=wet, B=ea): lane(lid,lg) -> edge lid, cols n*16+lg*4+q.
//   logit partials lane-local (xl[s_lid], xr[d] bf16 8B loads), 2-shfl reduce.
//   ev = exp(logit); denom in-register; aggregate cols l*4 via shfl-broadcast
//   of (ev, src) + coalesced 8B row reads. out = bias + agg/denom. No LDS.
// ---------------------------------------------------------------------------
__global__ __launch_bounds__(256)
void gat_fused(const float* __restrict__ ea,
               const unsigned short* __restrict__ wet,   // [256][64] bf16
               const unsigned short* __restrict__ xlb,   // [NN][256] bf16
               const unsigned short* __restrict__ xrb,   // [NN][256] bf16
               const float* __restrict__ att,            // [256]
               const int* __restrict__ src,
               const int* __restrict__ eid, const int* __restrict__ row_start,
               const float* __restrict__ bias, float* __restrict__ out) {
  const int wid = threadIdx.x >> 6;
  const int l   = threadIdx.x & 63;
  const int lid = l & 15, lg = l >> 4;
  const int d   = blockIdx.x * 4 + wid;          // NN = 12500*4 exact

  const int beg0 = row_start[d], end = row_start[d + 1];
  const unsigned short* xrp = xrb + (size_t)d * 256;

  float aggx = 0.f, aggy = 0.f, aggz = 0.f, aggw = 0.f;
  float dtot = 0.f;

  for (int beg = beg0; beg < end; beg += 16) {
    const int idx   = beg + lid;
    const bool valid = idx < end;
    const int e = eid[valid ? idx : end - 1];
    const int s = src[e];

    // B-frags: ea row e (fp32 -> bf16), k-slices lg*8 within each 32-k step
    const float* ap = ea + (size_t)e * 64 + lg * 8;
    const float4 b00 = *(const float4*)(ap);
    const float4 b01 = *(const float4*)(ap + 4);
    const float4 b10 = *(const float4*)(ap + 32);
    const float4 b11 = *(const float4*)(ap + 36);
    bf16x8 bf0, bf1;
    bf0[0]=f2bf(b00.x); bf0[1]=f2bf(b00.y); bf0[2]=f2bf(b00.z); bf0[3]=f2bf(b00.w);
    bf0[4]=f2bf(b01.x); bf0[5]=f2bf(b01.y); bf0[6]=f2bf(b01.z); bf0[7]=f2bf(b01.w);
    bf1[0]=f2bf(b10.x); bf1[1]=f2bf(b10.y); bf1[2]=f2bf(b10.z); bf1[3]=f2bf(b10.w);
    bf1[4]=f2bf(b11.x); bf1[5]=f2bf(b11.y); bf1[6]=f2bf(b11.z); bf1[7]=f2bf(b11.w);

    const unsigned short* xlp = xlb + (size_t)s * 256;

    float p0 = 0.f, p1 = 0.f, p2 = 0.f, p3 = 0.f;
#pragma unroll
    for (int n = 0; n < 16; ++n) {
      const unsigned short* wp = wet + (size_t)(n * 16 + lid) * 64 + lg * 8;
      const bf16x8 a0 = *(const bf16x8*)(wp);
      const bf16x8 a1 = *(const bf16x8*)(wp + 32);
      f32x4 acc = (f32x4){0.f, 0.f, 0.f, 0.f};
      acc = __builtin_amdgcn_mfma_f32_16x16x32_bf16(a0, bf0, acc, 0, 0, 0);
      acc = __builtin_amdgcn_mfma_f32_16x16x32_bf16(a1, bf1, acc, 0, 0, 0);

      const int c0 = n * 16 + lg * 4;
      const uint2 xu = *(const uint2*)(xlp + c0);
      const uint2 ru = *(const uint2*)(xrp + c0);
      const float4 at = *(const float4*)(att + c0);
      float v, pn = 0.f;
      v = acc[0] + bflo(xu.x) + bflo(ru.x); v = LRELU(v); pn += v * at.x;
      v = acc[1] + bfhi(xu.x) + bfhi(ru.x); v = LRELU(v); pn += v * at.y;
      v = acc[2] + bflo(xu.y) + bflo(ru.y); v = LRELU(v); pn += v * at.z;
      v = acc[3] + bfhi(xu.y) + bfhi(ru.y); v = LRELU(v); pn += v * at.w;
      if ((n >> 2) == 0) p0 += pn;
      else if ((n >> 2) == 1) p1 += pn;
      else if ((n >> 2) == 2) p2 += pn;
      else p3 += pn;
    }

    // reduce each head's partial across the 4 lg lanes (lid fixed)
    p0 += __shfl_xor(p0, 16); p0 += __shfl_xor(p0, 32);
    p1 += __shfl_xor(p1, 16); p1 += __shfl_xor(p1, 32);
    p2 += __shfl_xor(p2, 16); p2 += __shfl_xor(p2, 32);
    p3 += __shfl_xor(p3, 16); p3 += __shfl_xor(p3, 32);

    const float e0v = valid ? expf(p0) : 0.f;
    const float e1v = valid ? expf(p1) : 0.f;
    const float e2v = valid ? expf(p2) : 0.f;
    const float e3v = valid ? expf(p3) : 0.f;
    // my (edge=lid, head=lg) weight
    const float ev_mine = (lg == 0) ? e0v : (lg == 1) ? e1v
                        : (lg == 2) ? e2v : e3v;
    dtot += ev_mine;

    // aggregate: cols l*4 (head l>>4 == lg matches ev_mine's head)
    const int jmax = min(16, end - beg);
    const int base = l & 48;
    for (int j = 0; j < jmax; ++j) {
      const float evj = __shfl(ev_mine, base | j);
      const int   sj  = __shfl(s, base | j);
      const uint2 xv = *(const uint2*)(xlb + (size_t)sj * 256 + l * 4);
      aggx += evj * bflo(xv.x); aggy += evj * bfhi(xv.x);
      aggz += evj * bflo(xv.y); aggw += evj * bfhi(xv.y);
    }
  }

  // denom for head lg: sum dtot across the 16 lid lanes
  float den = dtot;
  den += __shfl_xor(den, 1); den += __shfl_xor(den, 2);
  den += __shfl_xor(den, 4); den += __shfl_xor(den, 8);
  const float inv = 1.f / (den + 1e-16f);

  const float4 bv = *(const float4*)(bias + l * 4);
  float4 o;
  o.x = bv.x + aggx * inv; o.y = bv.y + aggy * inv;
  o.z = bv.z + aggz * inv; o.w = bv.w + aggw * inv;
  *(float4*)(out + (size_t)d * 256 + l * 4) = o;
}

extern "C" void kernel_launch(void* const* d_in, const int* in_sizes, int n_in,
                              void* d_out, int out_size, void* d_ws, size_t ws_size,
                              hipStream_t stream) {
  const float* x    = (const float*)d_in[0];
  const int*   ei   = (const int*)d_in[1];
  const float* ea   = (const float*)d_in[2];
  const float* Wl1  = (const float*)d_in[3];
  const float* bl1  = (const float*)d_in[4];
  const float* Wr1  = (const float*)d_in[5];
  const float* br1  = (const float*)d_in[6];
  const float* We1  = (const float*)d_in[7];
  const float* att1 = (const float*)d_in[8];
  const float* bias1= (const float*)d_in[9];
  const float* Wl2  = (const float*)d_in[10];
  const float* bl2  = (const float*)d_in[11];
  const float* Wr2  = (const float*)d_in[12];
  const float* br2  = (const float*)d_in[13];
  const float* We2  = (const float*)d_in[14];
  const float* att2 = (const float*)d_in[15];
  const float* bias2= (const float*)d_in[16];

  float* out = (float*)d_out;
  unsigned short* wsb = (unsigned short*)d_ws;

  unsigned short* xlb  = wsb;                       // NN*256 bf16
  unsigned short* xrb  = xlb + (size_t)NN * 256;    // NN*256
  unsigned short* wet1 = xrb + (size_t)NN * 256;    // 16384
  unsigned short* wet2 = wet1 + 16384;              // 16384
  int* cur       = (int*)(wet2 + 16384);            // NN
  int* row_start = cur + NN;                        // NN+1
  int* eid       = row_start + NN + 1;              // NE
  float* h1 = out;  // d_out doubles as h1; fully consumed before final write

  const int* src = ei;
  const int* dst = ei + NE;

  const dim3 ggrid((NN + 63) / 64, 2);
  const int  epb   = (NE + 255) / 256;
  const int  fgrid = NN / 4;   // 12500

  // ---- prep: CSR + WeT bf16 ----
  hipMemsetAsync(cur, 0, NN * sizeof(int), stream);
  conv_wet<<<dim3(64, 2), 256, 0, stream>>>(We1, wet1, We2, wet2);
  dst_hist<<<epb, 256, 0, stream>>>(dst, cur);
  exscan<<<1, 1024, 0, stream>>>(cur, row_start, cur, NN);
  bucket_fill<<<epb, 256, 0, stream>>>(dst, cur, eid);

  // ---- layer 1 ----
  gemm_bias2<<<ggrid, 256, 0, stream>>>(x, Wl1, bl1, xlb, Wr1, br1, xrb,
                                        NN, 128);
  gat_fused<<<fgrid, 256, 0, stream>>>(ea, wet1, xlb, xrb, att1, src,
                                       eid, row_start, bias1, h1);

  // ---- layer 2 ----
  gemm_bias2<<<ggrid, 256, 0, stream>>>(h1, Wl2, bl2, xlb, Wr2, br2, xrb,
                                        NN, 256);
  gat_fused<<<fgrid, 256, 0, stream>>>(ea, wet2, xlb, xrb, att2, src,
                                       eid, row_start, bias2, out);
}

// Round 6
// 1439.108 us; speedup vs baseline: 1.4903x; 1.4903x over previous
//
#include <hip/hip_runtime.h>
#include <math.h>

#define NN 50000
#define NE 800000

#define LRELU(v) ((v) > 0.f ? (v) : 0.2f * (v))

typedef __attribute__((ext_vector_type(4))) float f32x4;
typedef __attribute__((ext_vector_type(8))) short bf16x8;

static __device__ __forceinline__ float bf2f(unsigned short u) {
  union { unsigned int i; float f; } c; c.i = ((unsigned int)u) << 16; return c.f;
}
static __device__ __forceinline__ unsigned short f2bf(float f) {
  union { float f; unsigned int i; } c; c.f = f;
  unsigned int r = c.i + 0x7fff + ((c.i >> 16) & 1);   // RNE
  return (unsigned short)(r >> 16);
}

// ---------------------------------------------------------------------------
// GEMM: out = A @ W + b. fp32 out (xl path) + bf16 copies for edge gathers.
// blockIdx.y: 0 -> (W0,b0): xl fp32 + xlb bf16; 1 -> (W1,b1): xrb bf16 only.
// ---------------------------------------------------------------------------
__global__ __launch_bounds__(256)
void gemm_bias2(const float* __restrict__ A,
                const float* __restrict__ W0, const float* __restrict__ b0,
                float* __restrict__ outf, unsigned short* __restrict__ outb0,
                const float* __restrict__ W1, const float* __restrict__ b1,
                unsigned short* __restrict__ outb1,
                int N, int K) {
  const float* W    = blockIdx.y ? W1 : W0;
  const float* bias = blockIdx.y ? b1 : b0;
  unsigned short* outb = blockIdx.y ? outb1 : outb0;
  float* outf_ = blockIdx.y ? nullptr : outf;

  __shared__ float As[32][68];
  __shared__ float Bs[32][256];

  const int tid  = threadIdx.x;
  const int c4   = (tid & 63) * 4;
  const int rg   = tid >> 6;
  const int row0 = blockIdx.x * 64;

  float acc[16][4];
#pragma unroll
  for (int i = 0; i < 16; ++i)
#pragma unroll
    for (int j = 0; j < 4; ++j) acc[i][j] = 0.f;

  for (int k0 = 0; k0 < K; k0 += 32) {
#pragma unroll
    for (int p = 0; p < 2; ++p) {
      const int r  = p * 32 + (tid >> 3);
      const int kq = (tid & 7) * 4;
      float4 v = make_float4(0.f, 0.f, 0.f, 0.f);
      const int grow = row0 + r;
      if (grow < N) v = *(const float4*)(A + (size_t)grow * K + k0 + kq);
      As[kq + 0][r] = v.x; As[kq + 1][r] = v.y;
      As[kq + 2][r] = v.z; As[kq + 3][r] = v.w;
    }
#pragma unroll
    for (int p = 0; p < 8; ++p) {
      const int lin = p * 1024 + tid * 4;
      const int kk = lin >> 8, cc = lin & 255;
      *(float4*)&Bs[kk][cc] = *(const float4*)(W + (size_t)(k0 + kk) * 256 + cc);
    }
    __syncthreads();
#pragma unroll
    for (int kk = 0; kk < 32; ++kk) {
      const float4 b = *(const float4*)&Bs[kk][c4];
      const float bb[4] = {b.x, b.y, b.z, b.w};
#pragma unroll
      for (int q = 0; q < 4; ++q) {
        const float4 a = *(const float4*)&As[kk][rg * 16 + q * 4];
        const float aa[4] = {a.x, a.y, a.z, a.w};
#pragma unroll
        for (int m = 0; m < 4; ++m)
#pragma unroll
          for (int j = 0; j < 4; ++j) acc[q * 4 + m][j] += aa[m] * bb[j];
      }
    }
    __syncthreads();
  }

  const float4 bv = *(const float4*)(bias + c4);
#pragma unroll
  for (int i = 0; i < 16; ++i) {
    const int row = row0 + rg * 16 + i;
    if (row < N) {
      float4 o;
      o.x = acc[i][0] + bv.x; o.y = acc[i][1] + bv.y;
      o.z = acc[i][2] + bv.z; o.w = acc[i][3] + bv.w;
      if (outf_) *(float4*)(outf_ + (size_t)row * 256 + c4) = o;
      ushort4 ob;
      ob.x = f2bf(o.x); ob.y = f2bf(o.y); ob.z = f2bf(o.z); ob.w = f2bf(o.w);
      *(ushort4*)(outb + (size_t)row * 256 + c4) = ob;
    }
  }
}

// ---------------------------------------------------------------------------
// WeT prep: wet[c*64+k] = bf16(We[k*256+c]).
// ---------------------------------------------------------------------------
__global__ __launch_bounds__(256)
void conv_wet(const float* __restrict__ We1, unsigned short* __restrict__ wet1,
              const float* __restrict__ We2, unsigned short* __restrict__ wet2) {
  const float* We = blockIdx.y ? We2 : We1;
  unsigned short* wet = blockIdx.y ? wet2 : wet1;
  const int idx = blockIdx.x * 256 + threadIdx.x;
  const int k = idx >> 8, c = idx & 255;
  wet[c * 64 + k] = f2bf(We[(size_t)k * 256 + c]);
}

// ---------------------------------------------------------------------------
// CSR build: histogram -> exclusive scan -> bucket fill (+ sorted src/dst)
// ---------------------------------------------------------------------------
__global__ __launch_bounds__(256)
void dst_hist(const int* __restrict__ dst, int* __restrict__ cnt) {
  const int e = blockIdx.x * 256 + threadIdx.x;
  if (e < NE) atomicAdd(&cnt[dst[e]], 1);
}

__global__ __launch_bounds__(1024)
void exscan(int* __restrict__ cnt, int* __restrict__ row_start,
            int* __restrict__ cur, int n) {
  __shared__ int buf[1024];
  __shared__ int carry;
  if (threadIdx.x == 0) carry = 0;
  __syncthreads();
  for (int base = 0; base < n; base += 1024) {
    const int i = base + threadIdx.x;
    const int v = (i < n) ? cnt[i] : 0;
    buf[threadIdx.x] = v;
    __syncthreads();
    for (int off = 1; off < 1024; off <<= 1) {
      const int t = (threadIdx.x >= off) ? buf[threadIdx.x - off] : 0;
      __syncthreads();
      buf[threadIdx.x] += t;
      __syncthreads();
    }
    const int excl = buf[threadIdx.x] - v + carry;
    if (i < n) { row_start[i] = excl; cur[i] = excl; }
    __syncthreads();
    if (threadIdx.x == 1023) carry += buf[1023];
    __syncthreads();
  }
  if (threadIdx.x == 0) row_start[n] = carry;
}

__global__ __launch_bounds__(256)
void bucket_fill(const int* __restrict__ src, const int* __restrict__ dst,
                 int* __restrict__ cur, int* __restrict__ eid,
                 int* __restrict__ ssrc, int* __restrict__ sdst) {
  const int e = blockIdx.x * 256 + threadIdx.x;
  if (e < NE) {
    const int d = dst[e];
    const int p = atomicAdd(&cur[d], 1);
    eid[p] = e;
    ssrc[p] = src[e];
    sdst[p] = d;
  }
}

// ---------------------------------------------------------------------------
// Edge kernel (MFMA) over CSR positions: block = 64 positions, 4 waves x 16.
// A frag row = ea[eid[p]]; xr gathers dst-clustered (cache-hot); writes
// elog[p*4+h] contiguously. No LDS, no atomics.
// ---------------------------------------------------------------------------
__global__ __launch_bounds__(256)
void edge_logits_mfma(const float* __restrict__ ea,
                      const unsigned short* __restrict__ wet,  // [256][64]
                      const unsigned short* __restrict__ xlb,  // [NN][256]
                      const unsigned short* __restrict__ xrb,
                      const float* __restrict__ att,           // [256]
                      const int* __restrict__ eid,
                      const int* __restrict__ ssrc, const int* __restrict__ sdst,
                      float* __restrict__ elog) {
  const int tid = threadIdx.x;
  const int w = tid >> 6, l = tid & 63;
  const int lg = l >> 4, lid = l & 15;
  const int p0 = blockIdx.x * 64 + w * 16;   // wave's 16 CSR positions

  // A frags: row ea[eid[p0+lid]], k = 32t + 8*lg + j  (fp32 -> bf16)
  const int erow = eid[p0 + lid];
  const float* ap = ea + (size_t)erow * 64 + lg * 8;
  const float4 a00 = *(const float4*)(ap);
  const float4 a01 = *(const float4*)(ap + 4);
  const float4 a10 = *(const float4*)(ap + 32);
  const float4 a11 = *(const float4*)(ap + 36);
  bf16x8 a0, a1;
  a0[0]=f2bf(a00.x); a0[1]=f2bf(a00.y); a0[2]=f2bf(a00.z); a0[3]=f2bf(a00.w);
  a0[4]=f2bf(a01.x); a0[5]=f2bf(a01.y); a0[6]=f2bf(a01.z); a0[7]=f2bf(a01.w);
  a1[0]=f2bf(a10.x); a1[1]=f2bf(a10.y); a1[2]=f2bf(a10.z); a1[3]=f2bf(a10.w);
  a1[4]=f2bf(a11.x); a1[5]=f2bf(a11.y); a1[6]=f2bf(a11.z); a1[7]=f2bf(a11.w);

  f32x4 acc[16];
#pragma unroll
  for (int n = 0; n < 16; ++n) acc[n] = (f32x4){0.f, 0.f, 0.f, 0.f};

#pragma unroll
  for (int n = 0; n < 16; ++n) {
    const unsigned short* bp = wet + (size_t)(n * 16 + lid) * 64 + lg * 8;
    const bf16x8 b0 = *(const bf16x8*)(bp);
    const bf16x8 b1 = *(const bf16x8*)(bp + 32);
    acc[n] = __builtin_amdgcn_mfma_f32_16x16x32_bf16(a0, b0, acc[n], 0, 0, 0);
    acc[n] = __builtin_amdgcn_mfma_f32_16x16x32_bf16(a1, b1, acc[n], 0, 0, 0);
  }

  // per-lane D rows: r -> position p0 + lg*4 + r
  int s[4], d[4];
#pragma unroll
  for (int r = 0; r < 4; ++r) {
    const int p = p0 + lg * 4 + r;
    s[r] = ssrc[p]; d[r] = sdst[p];
  }

  float plog[4][4];
#pragma unroll
  for (int r = 0; r < 4; ++r)
#pragma unroll
    for (int h = 0; h < 4; ++h) plog[r][h] = 0.f;

#pragma unroll
  for (int n = 0; n < 16; ++n) {
    const int col = n * 16 + lid;
    const float av = att[col];
    const int h = n >> 2;
#pragma unroll
    for (int r = 0; r < 4; ++r) {
      const float xlv = bf2f(xlb[(size_t)s[r] * 256 + col]);
      const float xrv = bf2f(xrb[(size_t)d[r] * 256 + col]);
      float m = acc[n][r] + xlv + xrv;
      m = LRELU(m);
      plog[r][h] += m * av;
    }
  }

  // reduce over the 16 lanes of each lg-group (they hold the 16 col-slices)
#pragma unroll
  for (int r = 0; r < 4; ++r)
#pragma unroll
    for (int h = 0; h < 4; ++h) {
      float v = plog[r][h];
#pragma unroll
      for (int sft = 8; sft >= 1; sft >>= 1) v += __shfl_xor(v, sft, 16);
      plog[r][h] = v;
    }

  // writer: lane lid handles (r = lid&3, h = lid>>2)
  float v = 0.f;
#pragma unroll
  for (int r = 0; r < 4; ++r)
#pragma unroll
    for (int h = 0; h < 4; ++h)
      if (lid == h * 4 + r) v = plog[r][h];

  const int p = p0 + lg * 4 + (lid & 3);
  const int h = lid >> 2;
  elog[(size_t)p * 4 + h] = expf(v);
}

// ---------------------------------------------------------------------------
// Aggregation: one wave per dst node, 4 nodes/block. Streams its CSR bucket
// sequentially (elog, ssrc position-ordered), computes denom in-register.
// out[d] = bias + (sum ev*xl[s]) / (sum ev)
// ---------------------------------------------------------------------------
__global__ __launch_bounds__(256)
void aggregate(const float* __restrict__ xl, const float* __restrict__ elog,
               const int* __restrict__ ssrc, const int* __restrict__ row_start,
               const float* __restrict__ bias, float* __restrict__ out) {
  const int wid  = threadIdx.x >> 6;
  const int lane = threadIdx.x & 63;
  const int d    = blockIdx.x * 4 + wid;      // NN = 12500*4 exact
  const int h = lane >> 4;
  const int c = lane * 4;
  float4 acc = make_float4(0.f, 0.f, 0.f, 0.f);
  float dtot = 0.f;
  const int beg = row_start[d], end = row_start[d + 1];
  for (int p = beg; p < end; ++p) {
    const float ev = elog[(size_t)p * 4 + h];
    const int s = ssrc[p];
    const float4 v = *(const float4*)(xl + (size_t)s * 256 + c);
    acc.x += ev * v.x; acc.y += ev * v.y;
    acc.z += ev * v.z; acc.w += ev * v.w;
    dtot += ev;
  }
  const float inv = 1.f / (dtot + 1e-16f);
  const float4 bv = *(const float4*)(bias + c);
  float4 o;
  o.x = bv.x + acc.x * inv; o.y = bv.y + acc.y * inv;
  o.z = bv.z + acc.z * inv; o.w = bv.w + acc.w * inv;
  *(float4*)(out + (size_t)d * 256 + c) = o;
}

extern "C" void kernel_launch(void* const* d_in, const int* in_sizes, int n_in,
                              void* d_out, int out_size, void* d_ws, size_t ws_size,
                              hipStream_t stream) {
  const float* x    = (const float*)d_in[0];
  const int*   ei   = (const int*)d_in[1];
  const float* ea   = (const float*)d_in[2];
  const float* Wl1  = (const float*)d_in[3];
  const float* bl1  = (const float*)d_in[4];
  const float* Wr1  = (const float*)d_in[5];
  const float* br1  = (const float*)d_in[6];
  const float* We1  = (const float*)d_in[7];
  const float* att1 = (const float*)d_in[8];
  const float* bias1= (const float*)d_in[9];
  const float* Wl2  = (const float*)d_in[10];
  const float* bl2  = (const float*)d_in[11];
  const float* Wr2  = (const float*)d_in[12];
  const float* br2  = (const float*)d_in[13];
  const float* We2  = (const float*)d_in[14];
  const float* att2 = (const float*)d_in[15];
  const float* bias2= (const float*)d_in[16];

  float* out = (float*)d_out;
  float* ws  = (float*)d_ws;

  float* xl    = ws;                                   // NN*256 f32
  float* elog  = xl + (size_t)NN * 256;                // NE*4 f32
  unsigned short* xlb  = (unsigned short*)(elog + (size_t)NE * 4); // NN*256
  unsigned short* xrb  = xlb + (size_t)NN * 256;       // NN*256
  unsigned short* wet1 = xrb + (size_t)NN * 256;       // 16384
  unsigned short* wet2 = wet1 + 16384;                 // 16384
  int* cur       = (int*)(wet2 + 16384);               // NN
  int* row_start = cur + NN;                           // NN+1
  int* eid       = row_start + NN + 1;                 // NE
  int* ssrc      = eid + NE;                           // NE
  int* sdst      = ssrc + NE;                          // NE
  float* h1 = out;  // d_out doubles as h1; fully consumed before final write

  const int* src = ei;
  const int* dst = ei + NE;

  const dim3 ggrid((NN + 63) / 64, 2);
  const int  egrid = NE / 64;        // 12500
  const int  epb   = (NE + 255) / 256;
  const int  agrid = NN / 4;         // 12500

  // ---- prep: CSR + WeT bf16 ----
  hipMemsetAsync(cur, 0, NN * sizeof(int), stream);
  conv_wet<<<dim3(64, 2), 256, 0, stream>>>(We1, wet1, We2, wet2);
  dst_hist<<<epb, 256, 0, stream>>>(dst, cur);
  exscan<<<1, 1024, 0, stream>>>(cur, row_start, cur, NN);
  bucket_fill<<<epb, 256, 0, stream>>>(src, dst, cur, eid, ssrc, sdst);

  // ---- layer 1 ----
  gemm_bias2<<<ggrid, 256, 0, stream>>>(x, Wl1, bl1, xl, xlb, Wr1, br1, xrb,
                                        NN, 128);
  edge_logits_mfma<<<egrid, 256, 0, stream>>>(ea, wet1, xlb, xrb, att1,
                                              eid, ssrc, sdst, elog);
  aggregate<<<agrid, 256, 0, stream>>>(xl, elog, ssrc, row_start, bias1, h1);

  // ---- layer 2 ----
  gemm_bias2<<<ggrid, 256, 0, stream>>>(h1, Wl2, bl2, xl, xlb, Wr2, br2, xrb,
                                        NN, 256);
  edge_logits_mfma<<<egrid, 256, 0, stream>>>(ea, wet2, xlb, xrb, att2,
                                              eid, ssrc, sdst, elog);
  aggregate<<<agrid, 256, 0, stream>>>(xl, elog, ssrc, row_start, bias2, out);
}

// Round 7
// 1328.485 us; speedup vs baseline: 1.6144x; 1.0833x over previous
//
#include <hip/hip_runtime.h>
#include <math.h>

#define NN 50000
#define NE 800000

#define LRELU(v) ((v) > 0.f ? (v) : 0.2f * (v))

typedef __attribute__((ext_vector_type(4))) float f32x4;
typedef __attribute__((ext_vector_type(8))) short bf16x8;

static __device__ __forceinline__ unsigned short f2bf(float f) {
  union { float f; unsigned int i; } c; c.f = f;
  unsigned int r = c.i + 0x7fff + ((c.i >> 16) & 1);   // RNE
  return (unsigned short)(r >> 16);
}
static __device__ __forceinline__ float bflo(unsigned int u) {
  union { unsigned int i; float f; } c; c.i = u << 16; return c.f;
}
static __device__ __forceinline__ float bfhi(unsigned int u) {
  union { unsigned int i; float f; } c; c.i = u & 0xffff0000u; return c.f;
}

// ---------------------------------------------------------------------------
// GEMM: outb = bf16(A @ W + b). blockIdx.y: 0 -> (W0,b0)->outb0, 1 -> outb1.
// BM=64, BN=256, BK=32, 256 threads.
// ---------------------------------------------------------------------------
__global__ __launch_bounds__(256)
void gemm_bias2(const float* __restrict__ A,
                const float* __restrict__ W0, const float* __restrict__ b0,
                unsigned short* __restrict__ outb0,
                const float* __restrict__ W1, const float* __restrict__ b1,
                unsigned short* __restrict__ outb1,
                int N, int K) {
  const float* W    = blockIdx.y ? W1 : W0;
  const float* bias = blockIdx.y ? b1 : b0;
  unsigned short* outb = blockIdx.y ? outb1 : outb0;

  __shared__ float As[32][68];
  __shared__ float Bs[32][256];

  const int tid  = threadIdx.x;
  const int c4   = (tid & 63) * 4;
  const int rg   = tid >> 6;
  const int row0 = blockIdx.x * 64;

  float acc[16][4];
#pragma unroll
  for (int i = 0; i < 16; ++i)
#pragma unroll
    for (int j = 0; j < 4; ++j) acc[i][j] = 0.f;

  for (int k0 = 0; k0 < K; k0 += 32) {
#pragma unroll
    for (int p = 0; p < 2; ++p) {
      const int r  = p * 32 + (tid >> 3);
      const int kq = (tid & 7) * 4;
      float4 v = make_float4(0.f, 0.f, 0.f, 0.f);
      const int grow = row0 + r;
      if (grow < N) v = *(const float4*)(A + (size_t)grow * K + k0 + kq);
      As[kq + 0][r] = v.x; As[kq + 1][r] = v.y;
      As[kq + 2][r] = v.z; As[kq + 3][r] = v.w;
    }
#pragma unroll
    for (int p = 0; p < 8; ++p) {
      const int lin = p * 1024 + tid * 4;
      const int kk = lin >> 8, cc = lin & 255;
      *(float4*)&Bs[kk][cc] = *(const float4*)(W + (size_t)(k0 + kk) * 256 + cc);
    }
    __syncthreads();
#pragma unroll
    for (int kk = 0; kk < 32; ++kk) {
      const float4 b = *(const float4*)&Bs[kk][c4];
      const float bb[4] = {b.x, b.y, b.z, b.w};
#pragma unroll
      for (int q = 0; q < 4; ++q) {
        const float4 a = *(const float4*)&As[kk][rg * 16 + q * 4];
        const float aa[4] = {a.x, a.y, a.z, a.w};
#pragma unroll
        for (int m = 0; m < 4; ++m)
#pragma unroll
          for (int j = 0; j < 4; ++j) acc[q * 4 + m][j] += aa[m] * bb[j];
      }
    }
    __syncthreads();
  }

  const float4 bv = *(const float4*)(bias + c4);
#pragma unroll
  for (int i = 0; i < 16; ++i) {
    const int row = row0 + rg * 16 + i;
    if (row < N) {
      ushort4 ob;
      ob.x = f2bf(acc[i][0] + bv.x); ob.y = f2bf(acc[i][1] + bv.y);
      ob.z = f2bf(acc[i][2] + bv.z); ob.w = f2bf(acc[i][3] + bv.w);
      *(ushort4*)(outb + (size_t)row * 256 + c4) = ob;
    }
  }
}

// ---------------------------------------------------------------------------
// WeT prep: wet[c*64+k] = bf16(We[k*256+c]).
// ---------------------------------------------------------------------------
__global__ __launch_bounds__(256)
void conv_wet(const float* __restrict__ We1, unsigned short* __restrict__ wet1,
              const float* __restrict__ We2, unsigned short* __restrict__ wet2) {
  const float* We = blockIdx.y ? We2 : We1;
  unsigned short* wet = blockIdx.y ? wet2 : wet1;
  const int idx = blockIdx.x * 256 + threadIdx.x;
  const int k = idx >> 8, c = idx & 255;
  wet[c * 64 + k] = f2bf(We[(size_t)k * 256 + c]);
}

// ---------------------------------------------------------------------------
// CSR build: histogram -> exclusive scan -> bucket fill (+ sorted src/dst)
// ---------------------------------------------------------------------------
__global__ __launch_bounds__(256)
void dst_hist(const int* __restrict__ dst, int* __restrict__ cnt) {
  const int e = blockIdx.x * 256 + threadIdx.x;
  if (e < NE) atomicAdd(&cnt[dst[e]], 1);
}

__global__ __launch_bounds__(1024)
void exscan(int* __restrict__ cnt, int* __restrict__ row_start,
            int* __restrict__ cur, int n) {
  __shared__ int buf[1024];
  __shared__ int carry;
  if (threadIdx.x == 0) carry = 0;
  __syncthreads();
  for (int base = 0; base < n; base += 1024) {
    const int i = base + threadIdx.x;
    const int v = (i < n) ? cnt[i] : 0;
    buf[threadIdx.x] = v;
    __syncthreads();
    for (int off = 1; off < 1024; off <<= 1) {
      const int t = (threadIdx.x >= off) ? buf[threadIdx.x - off] : 0;
      __syncthreads();
      buf[threadIdx.x] += t;
      __syncthreads();
    }
    const int excl = buf[threadIdx.x] - v + carry;
    if (i < n) { row_start[i] = excl; cur[i] = excl; }
    __syncthreads();
    if (threadIdx.x == 1023) carry += buf[1023];
    __syncthreads();
  }
  if (threadIdx.x == 0) row_start[n] = carry;
}

__global__ __launch_bounds__(256)
void bucket_fill(const int* __restrict__ src, const int* __restrict__ dst,
                 int* __restrict__ cur, int* __restrict__ eid,
                 int* __restrict__ ssrc, int* __restrict__ sdst) {
  const int e = blockIdx.x * 256 + threadIdx.x;
  if (e < NE) {
    const int d = dst[e];
    const int p = atomicAdd(&cur[d], 1);
    eid[p] = e;
    ssrc[p] = src[e];
    sdst[p] = d;
  }
}

// ---------------------------------------------------------------------------
// Edge kernel, swapped-operand MFMA (R5-validated layout), position-parallel.
// Block = 64 CSR positions, 4 waves x 16. mfma(A=wet, B=ea): lane (lid,lg)
// holds edge lid's cols n*16+lg*4+{0..3} -> per-n epilogue needs one 8B uint2
// from xlb[s] and xrb[d]; att-dot lane-local; 2 shfl_xor per head partial;
// contiguous elog write. No LDS, no atomics.
// ---------------------------------------------------------------------------
__global__ __launch_bounds__(256)
void edge_logits_swap(const float* __restrict__ ea,
                      const unsigned short* __restrict__ wet,  // [256][64]
                      const unsigned short* __restrict__ xlb,  // [NN][256]
                      const unsigned short* __restrict__ xrb,
                      const float* __restrict__ att,           // [256]
                      const int* __restrict__ eid,
                      const int* __restrict__ ssrc, const int* __restrict__ sdst,
                      float* __restrict__ elog) {
  const int tid = threadIdx.x;
  const int w = tid >> 6, l = tid & 63;
  const int lid = l & 15, lg = l >> 4;
  const int p0 = blockIdx.x * 64 + w * 16;   // wave's 16 CSR positions
  const int p  = p0 + lid;                   // my edge (per lid; dup over lg)
  const int e  = eid[p];
  const int s  = ssrc[p];
  const int d  = sdst[p];

  // B-frags: ea row e (fp32 -> bf16), k = 32t + lg*8 + j
  const float* ap = ea + (size_t)e * 64 + lg * 8;
  const float4 b00 = *(const float4*)(ap);
  const float4 b01 = *(const float4*)(ap + 4);
  const float4 b10 = *(const float4*)(ap + 32);
  const float4 b11 = *(const float4*)(ap + 36);
  bf16x8 bf0, bf1;
  bf0[0]=f2bf(b00.x); bf0[1]=f2bf(b00.y); bf0[2]=f2bf(b00.z); bf0[3]=f2bf(b00.w);
  bf0[4]=f2bf(b01.x); bf0[5]=f2bf(b01.y); bf0[6]=f2bf(b01.z); bf0[7]=f2bf(b01.w);
  bf1[0]=f2bf(b10.x); bf1[1]=f2bf(b10.y); bf1[2]=f2bf(b10.z); bf1[3]=f2bf(b10.w);
  bf1[4]=f2bf(b11.x); bf1[5]=f2bf(b11.y); bf1[6]=f2bf(b11.z); bf1[7]=f2bf(b11.w);

  const unsigned short* xlp = xlb + (size_t)s * 256;
  const unsigned short* xrp = xrb + (size_t)d * 256;

  float ph0 = 0.f, ph1 = 0.f, ph2 = 0.f, ph3 = 0.f;
#pragma unroll
  for (int n = 0; n < 16; ++n) {
    const unsigned short* wp = wet + (size_t)(n * 16 + lid) * 64 + lg * 8;
    const bf16x8 a0 = *(const bf16x8*)(wp);
    const bf16x8 a1 = *(const bf16x8*)(wp + 32);
    f32x4 acc = (f32x4){0.f, 0.f, 0.f, 0.f};
    acc = __builtin_amdgcn_mfma_f32_16x16x32_bf16(a0, bf0, acc, 0, 0, 0);
    acc = __builtin_amdgcn_mfma_f32_16x16x32_bf16(a1, bf1, acc, 0, 0, 0);

    const int c0 = n * 16 + lg * 4;
    const uint2 xu = *(const uint2*)(xlp + c0);
    const uint2 ru = *(const uint2*)(xrp + c0);
    const float4 at = *(const float4*)(att + c0);
    float v, pn = 0.f;
    v = acc[0] + bflo(xu.x) + bflo(ru.x); v = LRELU(v); pn += v * at.x;
    v = acc[1] + bfhi(xu.x) + bfhi(ru.x); v = LRELU(v); pn += v * at.y;
    v = acc[2] + bflo(xu.y) + bflo(ru.y); v = LRELU(v); pn += v * at.z;
    v = acc[3] + bfhi(xu.y) + bfhi(ru.y); v = LRELU(v); pn += v * at.w;
    if ((n >> 2) == 0) ph0 += pn;
    else if ((n >> 2) == 1) ph1 += pn;
    else if ((n >> 2) == 2) ph2 += pn;
    else ph3 += pn;
  }

  // reduce each head partial across the 4 lg groups (lid fixed)
  ph0 += __shfl_xor(ph0, 16); ph0 += __shfl_xor(ph0, 32);
  ph1 += __shfl_xor(ph1, 16); ph1 += __shfl_xor(ph1, 32);
  ph2 += __shfl_xor(ph2, 16); ph2 += __shfl_xor(ph2, 32);
  ph3 += __shfl_xor(ph3, 16); ph3 += __shfl_xor(ph3, 32);

  const float logit = (lg == 0) ? ph0 : (lg == 1) ? ph1
                    : (lg == 2) ? ph2 : ph3;
  elog[(size_t)p * 4 + lg] = expf(logit);   // 64 consecutive floats per wave
}

// ---------------------------------------------------------------------------
// Aggregation: one wave per dst node, 4 nodes/block; streams its CSR bucket
// sequentially, denom in-register. Reads bf16 xlb (R5-validated precision).
// out[d] = bias + (sum ev*xl[s]) / (sum ev)
// ---------------------------------------------------------------------------
__global__ __launch_bounds__(256)
void aggregate(const unsigned short* __restrict__ xlb,
               const float* __restrict__ elog,
               const int* __restrict__ ssrc, const int* __restrict__ row_start,
               const float* __restrict__ bias, float* __restrict__ out) {
  const int wid  = threadIdx.x >> 6;
  const int lane = threadIdx.x & 63;
  const int d    = blockIdx.x * 4 + wid;      // NN = 12500*4 exact
  const int h = lane >> 4;
  const int c = lane * 4;
  float ax = 0.f, ay = 0.f, az = 0.f, aw = 0.f;
  float dtot = 0.f;
  const int beg = row_start[d], end = row_start[d + 1];
  for (int p = beg; p < end; ++p) {
    const float ev = elog[(size_t)p * 4 + h];
    const int s = ssrc[p];
    const uint2 xv = *(const uint2*)(xlb + (size_t)s * 256 + c);
    ax += ev * bflo(xv.x); ay += ev * bfhi(xv.x);
    az += ev * bflo(xv.y); aw += ev * bfhi(xv.y);
    dtot += ev;
  }
  const float inv = 1.f / (dtot + 1e-16f);
  const float4 bv = *(const float4*)(bias + c);
  float4 o;
  o.x = bv.x + ax * inv; o.y = bv.y + ay * inv;
  o.z = bv.z + az * inv; o.w = bv.w + aw * inv;
  *(float4*)(out + (size_t)d * 256 + c) = o;
}

extern "C" void kernel_launch(void* const* d_in, const int* in_sizes, int n_in,
                              void* d_out, int out_size, void* d_ws, size_t ws_size,
                              hipStream_t stream) {
  const float* x    = (const float*)d_in[0];
  const int*   ei   = (const int*)d_in[1];
  const float* ea   = (const float*)d_in[2];
  const float* Wl1  = (const float*)d_in[3];
  const float* bl1  = (const float*)d_in[4];
  const float* Wr1  = (const float*)d_in[5];
  const float* br1  = (const float*)d_in[6];
  const float* We1  = (const float*)d_in[7];
  const float* att1 = (const float*)d_in[8];
  const float* bias1= (const float*)d_in[9];
  const float* Wl2  = (const float*)d_in[10];
  const float* bl2  = (const float*)d_in[11];
  const float* Wr2  = (const float*)d_in[12];
  const float* br2  = (const float*)d_in[13];
  const float* We2  = (const float*)d_in[14];
  const float* att2 = (const float*)d_in[15];
  const float* bias2= (const float*)d_in[16];

  float* out = (float*)d_out;
  float* ws  = (float*)d_ws;

  float* elog = ws;                                    // NE*4 f32
  unsigned short* xlb  = (unsigned short*)(elog + (size_t)NE * 4); // NN*256
  unsigned short* xrb  = xlb + (size_t)NN * 256;       // NN*256
  unsigned short* wet1 = xrb + (size_t)NN * 256;       // 16384
  unsigned short* wet2 = wet1 + 16384;                 // 16384
  int* cur       = (int*)(wet2 + 16384);               // NN
  int* row_start = cur + NN;                           // NN+1
  int* eid       = row_start + NN + 1;                 // NE
  int* ssrc      = eid + NE;                           // NE
  int* sdst      = ssrc + NE;                          // NE
  float* h1 = out;  // d_out doubles as h1; fully consumed before final write

  const int* src = ei;
  const int* dst = ei + NE;

  const dim3 ggrid((NN + 63) / 64, 2);
  const int  egrid = NE / 64;        // 12500
  const int  epb   = (NE + 255) / 256;
  const int  agrid = NN / 4;         // 12500

  // ---- prep: CSR + WeT bf16 ----
  hipMemsetAsync(cur, 0, NN * sizeof(int), stream);
  conv_wet<<<dim3(64, 2), 256, 0, stream>>>(We1, wet1, We2, wet2);
  dst_hist<<<epb, 256, 0, stream>>>(dst, cur);
  exscan<<<1, 1024, 0, stream>>>(cur, row_start, cur, NN);
  bucket_fill<<<epb, 256, 0, stream>>>(src, dst, cur, eid, ssrc, sdst);

  // ---- layer 1 ----
  gemm_bias2<<<ggrid, 256, 0, stream>>>(x, Wl1, bl1, xlb, Wr1, br1, xrb,
                                        NN, 128);
  edge_logits_swap<<<egrid, 256, 0, stream>>>(ea, wet1, xlb, xrb, att1,
                                              eid, ssrc, sdst, elog);
  aggregate<<<agrid, 256, 0, stream>>>(xlb, elog, ssrc, row_start, bias1, h1);

  // ---- layer 2 ----
  gemm_bias2<<<ggrid, 256, 0, stream>>>(h1, Wl2, bl2, xlb, Wr2, br2, xrb,
                                        NN, 256);
  edge_logits_swap<<<egrid, 256, 0, stream>>>(ea, wet2, xlb, xrb, att2,
                                              eid, ssrc, sdst, elog);
  aggregate<<<agrid, 256, 0, stream>>>(xlb, elog, ssrc, row_start, bias2, out);
}

// Round 8
// 1053.479 us; speedup vs baseline: 2.0359x; 1.2610x over previous
//
#include <hip/hip_runtime.h>
#include <math.h>

#define NN 50000
#define NE 800000

#define LRELU(v) ((v) > 0.f ? (v) : 0.2f * (v))

typedef __attribute__((ext_vector_type(4))) float f32x4;
typedef __attribute__((ext_vector_type(8))) short bf16x8;

static __device__ __forceinline__ unsigned short f2bf(float f) {
  union { float f; unsigned int i; } c; c.f = f;
  unsigned int r = c.i + 0x7fff + ((c.i >> 16) & 1);   // RNE
  return (unsigned short)(r >> 16);
}
static __device__ __forceinline__ float bflo(unsigned int u) {
  union { unsigned int i; float f; } c; c.i = u << 16; return c.f;
}
static __device__ __forceinline__ float bfhi(unsigned int u) {
  union { unsigned int i; float f; } c; c.i = u & 0xffff0000u; return c.f;
}

// ---------------------------------------------------------------------------
// GEMM: outb = bf16(A @ W + b). blockIdx.y: 0 -> (W0,b0)->outb0, 1 -> outb1.
// ---------------------------------------------------------------------------
__global__ __launch_bounds__(256)
void gemm_bias2(const float* __restrict__ A,
                const float* __restrict__ W0, const float* __restrict__ b0,
                unsigned short* __restrict__ outb0,
                const float* __restrict__ W1, const float* __restrict__ b1,
                unsigned short* __restrict__ outb1,
                int N, int K) {
  const float* W    = blockIdx.y ? W1 : W0;
  const float* bias = blockIdx.y ? b1 : b0;
  unsigned short* outb = blockIdx.y ? outb1 : outb0;

  __shared__ float As[32][68];
  __shared__ float Bs[32][256];

  const int tid  = threadIdx.x;
  const int c4   = (tid & 63) * 4;
  const int rg   = tid >> 6;
  const int row0 = blockIdx.x * 64;

  float acc[16][4];
#pragma unroll
  for (int i = 0; i < 16; ++i)
#pragma unroll
    for (int j = 0; j < 4; ++j) acc[i][j] = 0.f;

  for (int k0 = 0; k0 < K; k0 += 32) {
#pragma unroll
    for (int p = 0; p < 2; ++p) {
      const int r  = p * 32 + (tid >> 3);
      const int kq = (tid & 7) * 4;
      float4 v = make_float4(0.f, 0.f, 0.f, 0.f);
      const int grow = row0 + r;
      if (grow < N) v = *(const float4*)(A + (size_t)grow * K + k0 + kq);
      As[kq + 0][r] = v.x; As[kq + 1][r] = v.y;
      As[kq + 2][r] = v.z; As[kq + 3][r] = v.w;
    }
#pragma unroll
    for (int p = 0; p < 8; ++p) {
      const int lin = p * 1024 + tid * 4;
      const int kk = lin >> 8, cc = lin & 255;
      *(float4*)&Bs[kk][cc] = *(const float4*)(W + (size_t)(k0 + kk) * 256 + cc);
    }
    __syncthreads();
#pragma unroll
    for (int kk = 0; kk < 32; ++kk) {
      const float4 b = *(const float4*)&Bs[kk][c4];
      const float bb[4] = {b.x, b.y, b.z, b.w};
#pragma unroll
      for (int q = 0; q < 4; ++q) {
        const float4 a = *(const float4*)&As[kk][rg * 16 + q * 4];
        const float aa[4] = {a.x, a.y, a.z, a.w};
#pragma unroll
        for (int m = 0; m < 4; ++m)
#pragma unroll
          for (int j = 0; j < 4; ++j) acc[q * 4 + m][j] += aa[m] * bb[j];
      }
    }
    __syncthreads();
  }

  const float4 bv = *(const float4*)(bias + c4);
#pragma unroll
  for (int i = 0; i < 16; ++i) {
    const int row = row0 + rg * 16 + i;
    if (row < N) {
      ushort4 ob;
      ob.x = f2bf(acc[i][0] + bv.x); ob.y = f2bf(acc[i][1] + bv.y);
      ob.z = f2bf(acc[i][2] + bv.z); ob.w = f2bf(acc[i][3] + bv.w);
      *(ushort4*)(outb + (size_t)row * 256 + c4) = ob;
    }
  }
}

// ---------------------------------------------------------------------------
// WeT prep: wet[c*64+k] = bf16(We[k*256+c]).
// ---------------------------------------------------------------------------
__global__ __launch_bounds__(256)
void conv_wet(const float* __restrict__ We1, unsigned short* __restrict__ wet1,
              const float* __restrict__ We2, unsigned short* __restrict__ wet2) {
  const float* We = blockIdx.y ? We2 : We1;
  unsigned short* wet = blockIdx.y ? wet2 : wet1;
  const int idx = blockIdx.x * 256 + threadIdx.x;
  const int k = idx >> 8, c = idx & 255;
  wet[c * 64 + k] = f2bf(We[(size_t)k * 256 + c]);
}

// ---------------------------------------------------------------------------
// CSR build
// ---------------------------------------------------------------------------
__global__ __launch_bounds__(256)
void dst_hist(const int* __restrict__ dst, int* __restrict__ cnt) {
  const int e = blockIdx.x * 256 + threadIdx.x;
  if (e < NE) atomicAdd(&cnt[dst[e]], 1);
}

__global__ __launch_bounds__(1024)
void exscan(int* __restrict__ cnt, int* __restrict__ row_start,
            int* __restrict__ cur, int n) {
  __shared__ int buf[1024];
  __shared__ int carry;
  if (threadIdx.x == 0) carry = 0;
  __syncthreads();
  for (int base = 0; base < n; base += 1024) {
    const int i = base + threadIdx.x;
    const int v = (i < n) ? cnt[i] : 0;
    buf[threadIdx.x] = v;
    __syncthreads();
    for (int off = 1; off < 1024; off <<= 1) {
      const int t = (threadIdx.x >= off) ? buf[threadIdx.x - off] : 0;
      __syncthreads();
      buf[threadIdx.x] += t;
      __syncthreads();
    }
    const int excl = buf[threadIdx.x] - v + carry;
    if (i < n) { row_start[i] = excl; cur[i] = excl; }
    __syncthreads();
    if (threadIdx.x == 1023) carry += buf[1023];
    __syncthreads();
  }
  if (threadIdx.x == 0) row_start[n] = carry;
}

__global__ __launch_bounds__(256)
void bucket_fill(const int* __restrict__ src, const int* __restrict__ dst,
                 int* __restrict__ cur, int* __restrict__ eid,
                 int* __restrict__ ssrc, int* __restrict__ sdst) {
  const int e = blockIdx.x * 256 + threadIdx.x;
  if (e < NE) {
    const int d = dst[e];
    const int p = atomicAdd(&cur[d], 1);
    eid[p] = e;
    ssrc[p] = src[e];
    sdst[p] = d;
  }
}

// ---------------------------------------------------------------------------
// eab prep: eab[p][c] = bf16(ea[eid[p]][c]) — CSR-position-ordered bf16 copy.
// ---------------------------------------------------------------------------
__global__ __launch_bounds__(256)
void conv_eab(const float* __restrict__ ea, const int* __restrict__ eid,
              unsigned short* __restrict__ eab) {
  const int g = blockIdx.x * 256 + threadIdx.x;   // NE*16 threads
  const int p = g >> 4, c4 = (g & 15) * 4;
  const int e = eid[p];
  const float4 v = *(const float4*)(ea + (size_t)e * 64 + c4);
  ushort4 o;
  o.x = f2bf(v.x); o.y = f2bf(v.y); o.z = f2bf(v.z); o.w = f2bf(v.w);
  *(ushort4*)(eab + (size_t)p * 64 + c4) = o;
}

// ---------------------------------------------------------------------------
// Edge kernel, swapped-operand MFMA + wet staged in LDS (fragment order).
// Block = 64 CSR positions, 4 waves x 16. EAB=1: dense bf16 ea reads.
// ---------------------------------------------------------------------------
template <int EAB>
__global__ __launch_bounds__(256)
void edge_logits_swap(const float* __restrict__ ea,
                      const unsigned short* __restrict__ eab,  // [NE][64] bf16
                      const unsigned short* __restrict__ wet,  // [256][64]
                      const unsigned short* __restrict__ xlb,  // [NN][256]
                      const unsigned short* __restrict__ xrb,
                      const float* __restrict__ att,           // [256]
                      const int* __restrict__ eid,
                      const int* __restrict__ ssrc, const int* __restrict__ sdst,
                      float* __restrict__ elog) {
  // fragment-ordered wet: smw[half][n][lane][8]; lane reads base + 16*lane
  __shared__ unsigned short smw[2][16][64][8];   // 32 KB

  const int tid = threadIdx.x;
  // stage wet -> smw: 2048 16B-chunks; chunk -> (row r, 16B piece c)
#pragma unroll
  for (int i = 0; i < 8; ++i) {
    const int chunk = i * 256 + tid;
    const int r = chunk >> 3, c = chunk & 7;     // r: wet row (col of We)
    const int n = r >> 4, lid = r & 15;
    const int half = c >> 2, lg = c & 3;
    const uint4 v = *(const uint4*)(wet + (size_t)r * 64 + c * 8);
    *(uint4*)&smw[half][n][lg * 16 + lid][0] = v;
  }
  __syncthreads();

  const int w = tid >> 6, l = tid & 63;
  const int lid = l & 15, lg = l >> 4;
  const int p0 = blockIdx.x * 64 + w * 16;
  const int p  = p0 + lid;                   // my edge (per lid; dup over lg)
  const int s  = ssrc[p];
  const int d  = sdst[p];

  // B-frags: k = 32t + lg*8 + j
  bf16x8 bf0, bf1;
  if (EAB) {
    bf0 = *(const bf16x8*)(eab + (size_t)p * 64 + lg * 8);
    bf1 = *(const bf16x8*)(eab + (size_t)p * 64 + 32 + lg * 8);
  } else {
    const int e = eid[p];
    const float* ap = ea + (size_t)e * 64 + lg * 8;
    const float4 b00 = *(const float4*)(ap);
    const float4 b01 = *(const float4*)(ap + 4);
    const float4 b10 = *(const float4*)(ap + 32);
    const float4 b11 = *(const float4*)(ap + 36);
    bf0[0]=f2bf(b00.x); bf0[1]=f2bf(b00.y); bf0[2]=f2bf(b00.z); bf0[3]=f2bf(b00.w);
    bf0[4]=f2bf(b01.x); bf0[5]=f2bf(b01.y); bf0[6]=f2bf(b01.z); bf0[7]=f2bf(b01.w);
    bf1[0]=f2bf(b10.x); bf1[1]=f2bf(b10.y); bf1[2]=f2bf(b10.z); bf1[3]=f2bf(b10.w);
    bf1[4]=f2bf(b11.x); bf1[5]=f2bf(b11.y); bf1[6]=f2bf(b11.z); bf1[7]=f2bf(b11.w);
  }

  const unsigned short* xlp = xlb + (size_t)s * 256;
  const unsigned short* xrp = xrb + (size_t)d * 256;

  float ph0 = 0.f, ph1 = 0.f, ph2 = 0.f, ph3 = 0.f;
#pragma unroll
  for (int n = 0; n < 16; ++n) {
    const bf16x8 a0 = *(const bf16x8*)&smw[0][n][l][0];
    const bf16x8 a1 = *(const bf16x8*)&smw[1][n][l][0];
    f32x4 acc = (f32x4){0.f, 0.f, 0.f, 0.f};
    acc = __builtin_amdgcn_mfma_f32_16x16x32_bf16(a0, bf0, acc, 0, 0, 0);
    acc = __builtin_amdgcn_mfma_f32_16x16x32_bf16(a1, bf1, acc, 0, 0, 0);

    const int c0 = n * 16 + lg * 4;
    const uint2 xu = *(const uint2*)(xlp + c0);
    const uint2 ru = *(const uint2*)(xrp + c0);
    const float4 at = *(const float4*)(att + c0);
    float v, pn = 0.f;
    v = acc[0] + bflo(xu.x) + bflo(ru.x); v = LRELU(v); pn += v * at.x;
    v = acc[1] + bfhi(xu.x) + bfhi(ru.x); v = LRELU(v); pn += v * at.y;
    v = acc[2] + bflo(xu.y) + bflo(ru.y); v = LRELU(v); pn += v * at.z;
    v = acc[3] + bfhi(xu.y) + bfhi(ru.y); v = LRELU(v); pn += v * at.w;
    if ((n >> 2) == 0) ph0 += pn;
    else if ((n >> 2) == 1) ph1 += pn;
    else if ((n >> 2) == 2) ph2 += pn;
    else ph3 += pn;
  }

  ph0 += __shfl_xor(ph0, 16); ph0 += __shfl_xor(ph0, 32);
  ph1 += __shfl_xor(ph1, 16); ph1 += __shfl_xor(ph1, 32);
  ph2 += __shfl_xor(ph2, 16); ph2 += __shfl_xor(ph2, 32);
  ph3 += __shfl_xor(ph3, 16); ph3 += __shfl_xor(ph3, 32);

  const float logit = (lg == 0) ? ph0 : (lg == 1) ? ph1
                    : (lg == 2) ? ph2 : ph3;
  elog[(size_t)p * 4 + lg] = expf(logit);
}

// ---------------------------------------------------------------------------
// Aggregation: one wave per dst node, 4 nodes/block; streams CSR bucket.
// ---------------------------------------------------------------------------
__global__ __launch_bounds__(256)
void aggregate(const unsigned short* __restrict__ xlb,
               const float* __restrict__ elog,
               const int* __restrict__ ssrc, const int* __restrict__ row_start,
               const float* __restrict__ bias, float* __restrict__ out) {
  const int wid  = threadIdx.x >> 6;
  const int lane = threadIdx.x & 63;
  const int d    = blockIdx.x * 4 + wid;
  const int h = lane >> 4;
  const int c = lane * 4;
  float ax = 0.f, ay = 0.f, az = 0.f, aw = 0.f;
  float dtot = 0.f;
  const int beg = row_start[d], end = row_start[d + 1];
  for (int p = beg; p < end; ++p) {
    const float ev = elog[(size_t)p * 4 + h];
    const int s = ssrc[p];
    const uint2 xv = *(const uint2*)(xlb + (size_t)s * 256 + c);
    ax += ev * bflo(xv.x); ay += ev * bfhi(xv.x);
    az += ev * bflo(xv.y); aw += ev * bfhi(xv.y);
    dtot += ev;
  }
  const float inv = 1.f / (dtot + 1e-16f);
  const float4 bv = *(const float4*)(bias + c);
  float4 o;
  o.x = bv.x + ax * inv; o.y = bv.y + ay * inv;
  o.z = bv.z + az * inv; o.w = bv.w + aw * inv;
  *(float4*)(out + (size_t)d * 256 + c) = o;
}

extern "C" void kernel_launch(void* const* d_in, const int* in_sizes, int n_in,
                              void* d_out, int out_size, void* d_ws, size_t ws_size,
                              hipStream_t stream) {
  const float* x    = (const float*)d_in[0];
  const int*   ei   = (const int*)d_in[1];
  const float* ea   = (const float*)d_in[2];
  const float* Wl1  = (const float*)d_in[3];
  const float* bl1  = (const float*)d_in[4];
  const float* Wr1  = (const float*)d_in[5];
  const float* br1  = (const float*)d_in[6];
  const float* We1  = (const float*)d_in[7];
  const float* att1 = (const float*)d_in[8];
  const float* bias1= (const float*)d_in[9];
  const float* Wl2  = (const float*)d_in[10];
  const float* bl2  = (const float*)d_in[11];
  const float* Wr2  = (const float*)d_in[12];
  const float* br2  = (const float*)d_in[13];
  const float* We2  = (const float*)d_in[14];
  const float* att2 = (const float*)d_in[15];
  const float* bias2= (const float*)d_in[16];

  float* out = (float*)d_out;
  float* ws  = (float*)d_ws;

  float* elog = ws;                                    // NE*4 f32
  unsigned short* xlb  = (unsigned short*)(elog + (size_t)NE * 4); // NN*256
  unsigned short* xrb  = xlb + (size_t)NN * 256;       // NN*256
  unsigned short* wet1 = xrb + (size_t)NN * 256;       // 16384
  unsigned short* wet2 = wet1 + 16384;                 // 16384
  int* cur       = (int*)(wet2 + 16384);               // NN
  int* row_start = cur + NN;                           // NN+1
  int* eid       = row_start + NN + 1;                 // NE
  int* ssrc      = eid + NE;                           // NE
  int* sdst      = ssrc + NE;                          // NE
  unsigned short* eab = (unsigned short*)(sdst + NE);  // NE*64 bf16 (optional)
  const size_t need_eab =
      ((char*)(eab + (size_t)NE * 64)) - (char*)d_ws;
  const bool use_eab = ws_size >= need_eab;
  float* h1 = out;  // d_out doubles as h1

  const int* src = ei;
  const int* dst = ei + NE;

  const dim3 ggrid((NN + 63) / 64, 2);
  const int  egrid = NE / 64;        // 12500
  const int  epb   = (NE + 255) / 256;
  const int  agrid = NN / 4;         // 12500

  // ---- prep: CSR + WeT bf16 (+ eab) ----
  hipMemsetAsync(cur, 0, NN * sizeof(int), stream);
  conv_wet<<<dim3(64, 2), 256, 0, stream>>>(We1, wet1, We2, wet2);
  dst_hist<<<epb, 256, 0, stream>>>(dst, cur);
  exscan<<<1, 1024, 0, stream>>>(cur, row_start, cur, NN);
  bucket_fill<<<epb, 256, 0, stream>>>(src, dst, cur, eid, ssrc, sdst);
  if (use_eab)
    conv_eab<<<NE * 16 / 256, 256, 0, stream>>>(ea, eid, eab);

  // ---- layer 1 ----
  gemm_bias2<<<ggrid, 256, 0, stream>>>(x, Wl1, bl1, xlb, Wr1, br1, xrb,
                                        NN, 128);
  if (use_eab)
    edge_logits_swap<1><<<egrid, 256, 0, stream>>>(ea, eab, wet1, xlb, xrb,
                                                   att1, eid, ssrc, sdst, elog);
  else
    edge_logits_swap<0><<<egrid, 256, 0, stream>>>(ea, eab, wet1, xlb, xrb,
                                                   att1, eid, ssrc, sdst, elog);
  aggregate<<<agrid, 256, 0, stream>>>(xlb, elog, ssrc, row_start, bias1, h1);

  // ---- layer 2 ----
  gemm_bias2<<<ggrid, 256, 0, stream>>>(h1, Wl2, bl2, xlb, Wr2, br2, xrb,
                                        NN, 256);
  if (use_eab)
    edge_logits_swap<1><<<egrid, 256, 0, stream>>>(ea, eab, wet2, xlb, xrb,
                                                   att2, eid, ssrc, sdst, elog);
  else
    edge_logits_swap<0><<<egrid, 256, 0, stream>>>(ea, eab, wet2, xlb, xrb,
                                                   att2, eid, ssrc, sdst, elog);
  aggregate<<<agrid, 256, 0, stream>>>(xlb, elog, ssrc, row_start, bias2, out);
}

// Round 9
// 916.097 us; speedup vs baseline: 2.3412x; 1.1500x over previous
//
#include <hip/hip_runtime.h>
#include <math.h>

#define NN 50000
#define NE 800000

#define LRELU(v) ((v) > 0.f ? (v) : 0.2f * (v))

typedef __attribute__((ext_vector_type(4))) float f32x4;
typedef __attribute__((ext_vector_type(8))) short bf16x8;

static __device__ __forceinline__ unsigned short f2bf(float f) {
  union { float f; unsigned int i; } c; c.f = f;
  unsigned int r = c.i + 0x7fff + ((c.i >> 16) & 1);   // RNE
  return (unsigned short)(r >> 16);
}
static __device__ __forceinline__ float bflo(unsigned int u) {
  union { unsigned int i; float f; } c; c.i = u << 16; return c.f;
}
static __device__ __forceinline__ float bfhi(unsigned int u) {
  union { unsigned int i; float f; } c; c.i = u & 0xffff0000u; return c.f;
}

// ---------------------------------------------------------------------------
// conv_wf: W [K][256] fp32 -> fragment-ordered bf16 table
//   wf[((ks*16+n)*64 + l)*8 + j] = bf16(W[ks*32 + (l>>4)*8 + j][n*16 + (l&15)])
// One-time prep; makes in-GEMM A-frag loads lane-linear (1KB/instr coalesced).
// ---------------------------------------------------------------------------
__global__ __launch_bounds__(256)
void conv_wf(const float* __restrict__ W, unsigned short* __restrict__ wf,
             int K) {
  const int g = blockIdx.x * 256 + threadIdx.x;   // K*256 total
  if (g >= K * 256) return;
  const int j = g & 7;
  const int l = (g >> 3) & 63;
  const int fn = g >> 9;
  const int n = fn & 15, ks = fn >> 4;
  const int k = ks * 32 + (l >> 4) * 8 + j;
  const int c = n * 16 + (l & 15);
  wf[g] = f2bf(W[(size_t)k * 256 + c]);
}

// ---------------------------------------------------------------------------
// MFMA node GEMM: outb = bf16(A @ W + b). blockIdx.y picks (wf0,b0)/(wf1,b1).
// 64 rows/block, 4 waves x 16 rows. A-frags streamed from fragment-ordered
// wf (global, L2-resident, coalesced); B-frags = node rows fp32->bf16 in reg.
// D: lane(lid,lg) reg r = out[row0+w*16+lid][n*16+lg*4+r]. No LDS.
// ---------------------------------------------------------------------------
template <int KS>   // KS = K/32
__global__ __launch_bounds__(256)
void gemm_mfma(const float* __restrict__ A,
               const unsigned short* __restrict__ wf0,
               const float* __restrict__ b0, unsigned short* __restrict__ outb0,
               const unsigned short* __restrict__ wf1,
               const float* __restrict__ b1, unsigned short* __restrict__ outb1) {
  const unsigned short* wf = blockIdx.y ? wf1 : wf0;
  const float* bias        = blockIdx.y ? b1 : b0;
  unsigned short* outb     = blockIdx.y ? outb1 : outb0;

  const int tid = threadIdx.x;
  const int w = tid >> 6, l = tid & 63;
  const int lid = l & 15, lg = l >> 4;
  const int row  = blockIdx.x * 64 + w * 16 + lid;
  const bool rowok = row < NN;                 // uniform per wave (NN%16==0)
  const int rowv = rowok ? row : NN - 1;
  const int K = KS * 32;

  // B-frags: my node row, k = ks*32 + lg*8 + j
  bf16x8 bfr[KS];
  const float* ap = A + (size_t)rowv * K + lg * 8;
#pragma unroll
  for (int ks = 0; ks < KS; ++ks) {
    const float4 v0 = *(const float4*)(ap + ks * 32);
    const float4 v1 = *(const float4*)(ap + ks * 32 + 4);
    bf16x8 b;
    b[0]=f2bf(v0.x); b[1]=f2bf(v0.y); b[2]=f2bf(v0.z); b[3]=f2bf(v0.w);
    b[4]=f2bf(v1.x); b[5]=f2bf(v1.y); b[6]=f2bf(v1.z); b[7]=f2bf(v1.w);
    bfr[ks] = b;
  }

  f32x4 acc[16];
#pragma unroll
  for (int n = 0; n < 16; ++n) acc[n] = (f32x4){0.f, 0.f, 0.f, 0.f};

#pragma unroll
  for (int ks = 0; ks < KS; ++ks) {
#pragma unroll
    for (int n = 0; n < 16; ++n) {
      const bf16x8 a = *(const bf16x8*)(wf + ((size_t)(ks * 16 + n) * 64 + l) * 8);
      acc[n] = __builtin_amdgcn_mfma_f32_16x16x32_bf16(a, bfr[ks], acc[n], 0, 0, 0);
    }
  }

  if (rowok) {
#pragma unroll
    for (int n = 0; n < 16; ++n) {
      const int c0 = n * 16 + lg * 4;
      const float4 bv = *(const float4*)(bias + c0);
      ushort4 o;
      o.x = f2bf(acc[n][0] + bv.x); o.y = f2bf(acc[n][1] + bv.y);
      o.z = f2bf(acc[n][2] + bv.z); o.w = f2bf(acc[n][3] + bv.w);
      *(ushort4*)(outb + (size_t)row * 256 + c0) = o;
    }
  }
}

// ---------------------------------------------------------------------------
// WeT prep: wet[c*64+k] = bf16(We[k*256+c]).
// ---------------------------------------------------------------------------
__global__ __launch_bounds__(256)
void conv_wet(const float* __restrict__ We1, unsigned short* __restrict__ wet1,
              const float* __restrict__ We2, unsigned short* __restrict__ wet2) {
  const float* We = blockIdx.y ? We2 : We1;
  unsigned short* wet = blockIdx.y ? wet2 : wet1;
  const int idx = blockIdx.x * 256 + threadIdx.x;
  const int k = idx >> 8, c = idx & 255;
  wet[c * 64 + k] = f2bf(We[(size_t)k * 256 + c]);
}

// ---------------------------------------------------------------------------
// CSR build
// ---------------------------------------------------------------------------
__global__ __launch_bounds__(256)
void dst_hist(const int* __restrict__ dst, int* __restrict__ cnt) {
  const int e = blockIdx.x * 256 + threadIdx.x;
  if (e < NE) atomicAdd(&cnt[dst[e]], 1);
}

__global__ __launch_bounds__(1024)
void exscan(int* __restrict__ cnt, int* __restrict__ row_start,
            int* __restrict__ cur, int n) {
  __shared__ int buf[1024];
  __shared__ int carry;
  if (threadIdx.x == 0) carry = 0;
  __syncthreads();
  for (int base = 0; base < n; base += 1024) {
    const int i = base + threadIdx.x;
    const int v = (i < n) ? cnt[i] : 0;
    buf[threadIdx.x] = v;
    __syncthreads();
    for (int off = 1; off < 1024; off <<= 1) {
      const int t = (threadIdx.x >= off) ? buf[threadIdx.x - off] : 0;
      __syncthreads();
      buf[threadIdx.x] += t;
      __syncthreads();
    }
    const int excl = buf[threadIdx.x] - v + carry;
    if (i < n) { row_start[i] = excl; cur[i] = excl; }
    __syncthreads();
    if (threadIdx.x == 1023) carry += buf[1023];
    __syncthreads();
  }
  if (threadIdx.x == 0) row_start[n] = carry;
}

__global__ __launch_bounds__(256)
void bucket_fill(const int* __restrict__ src, const int* __restrict__ dst,
                 int* __restrict__ cur, int* __restrict__ eid,
                 int* __restrict__ ssrc, int* __restrict__ sdst) {
  const int e = blockIdx.x * 256 + threadIdx.x;
  if (e < NE) {
    const int d = dst[e];
    const int p = atomicAdd(&cur[d], 1);
    eid[p] = e;
    ssrc[p] = src[e];
    sdst[p] = d;
  }
}

// ---------------------------------------------------------------------------
// eab prep: eab[p][c] = bf16(ea[eid[p]][c]).
// ---------------------------------------------------------------------------
__global__ __launch_bounds__(256)
void conv_eab(const float* __restrict__ ea, const int* __restrict__ eid,
              unsigned short* __restrict__ eab) {
  const int g = blockIdx.x * 256 + threadIdx.x;
  const int p = g >> 4, c4 = (g & 15) * 4;
  const int e = eid[p];
  const float4 v = *(const float4*)(ea + (size_t)e * 64 + c4);
  ushort4 o;
  o.x = f2bf(v.x); o.y = f2bf(v.y); o.z = f2bf(v.z); o.w = f2bf(v.w);
  *(ushort4*)(eab + (size_t)p * 64 + c4) = o;
}

// ---------------------------------------------------------------------------
// Edge kernel, swapped-operand MFMA + wet staged in LDS (fragment order).
// ---------------------------------------------------------------------------
template <int EAB>
__global__ __launch_bounds__(256)
void edge_logits_swap(const float* __restrict__ ea,
                      const unsigned short* __restrict__ eab,
                      const unsigned short* __restrict__ wet,  // [256][64]
                      const unsigned short* __restrict__ xlb,
                      const unsigned short* __restrict__ xrb,
                      const float* __restrict__ att,
                      const int* __restrict__ eid,
                      const int* __restrict__ ssrc, const int* __restrict__ sdst,
                      float* __restrict__ elog) {
  __shared__ unsigned short smw[2][16][64][8];   // 32 KB

  const int tid = threadIdx.x;
#pragma unroll
  for (int i = 0; i < 8; ++i) {
    const int chunk = i * 256 + tid;
    const int r = chunk >> 3, c = chunk & 7;
    const int n = r >> 4, lid = r & 15;
    const int half = c >> 2, lg = c & 3;
    const uint4 v = *(const uint4*)(wet + (size_t)r * 64 + c * 8);
    *(uint4*)&smw[half][n][lg * 16 + lid][0] = v;
  }
  __syncthreads();

  const int w = tid >> 6, l = tid & 63;
  const int lid = l & 15, lg = l >> 4;
  const int p0 = blockIdx.x * 64 + w * 16;
  const int p  = p0 + lid;
  const int s  = ssrc[p];
  const int d  = sdst[p];

  bf16x8 bf0, bf1;
  if (EAB) {
    bf0 = *(const bf16x8*)(eab + (size_t)p * 64 + lg * 8);
    bf1 = *(const bf16x8*)(eab + (size_t)p * 64 + 32 + lg * 8);
  } else {
    const int e = eid[p];
    const float* ap = ea + (size_t)e * 64 + lg * 8;
    const float4 b00 = *(const float4*)(ap);
    const float4 b01 = *(const float4*)(ap + 4);
    const float4 b10 = *(const float4*)(ap + 32);
    const float4 b11 = *(const float4*)(ap + 36);
    bf0[0]=f2bf(b00.x); bf0[1]=f2bf(b00.y); bf0[2]=f2bf(b00.z); bf0[3]=f2bf(b00.w);
    bf0[4]=f2bf(b01.x); bf0[5]=f2bf(b01.y); bf0[6]=f2bf(b01.z); bf0[7]=f2bf(b01.w);
    bf1[0]=f2bf(b10.x); bf1[1]=f2bf(b10.y); bf1[2]=f2bf(b10.z); bf1[3]=f2bf(b10.w);
    bf1[4]=f2bf(b11.x); bf1[5]=f2bf(b11.y); bf1[6]=f2bf(b11.z); bf1[7]=f2bf(b11.w);
  }

  const unsigned short* xlp = xlb + (size_t)s * 256;
  const unsigned short* xrp = xrb + (size_t)d * 256;

  float ph0 = 0.f, ph1 = 0.f, ph2 = 0.f, ph3 = 0.f;
#pragma unroll
  for (int n = 0; n < 16; ++n) {
    const bf16x8 a0 = *(const bf16x8*)&smw[0][n][l][0];
    const bf16x8 a1 = *(const bf16x8*)&smw[1][n][l][0];
    f32x4 acc = (f32x4){0.f, 0.f, 0.f, 0.f};
    acc = __builtin_amdgcn_mfma_f32_16x16x32_bf16(a0, bf0, acc, 0, 0, 0);
    acc = __builtin_amdgcn_mfma_f32_16x16x32_bf16(a1, bf1, acc, 0, 0, 0);

    const int c0 = n * 16 + lg * 4;
    const uint2 xu = *(const uint2*)(xlp + c0);
    const uint2 ru = *(const uint2*)(xrp + c0);
    const float4 at = *(const float4*)(att + c0);
    float v, pn = 0.f;
    v = acc[0] + bflo(xu.x) + bflo(ru.x); v = LRELU(v); pn += v * at.x;
    v = acc[1] + bfhi(xu.x) + bfhi(ru.x); v = LRELU(v); pn += v * at.y;
    v = acc[2] + bflo(xu.y) + bflo(ru.y); v = LRELU(v); pn += v * at.z;
    v = acc[3] + bfhi(xu.y) + bfhi(ru.y); v = LRELU(v); pn += v * at.w;
    if ((n >> 2) == 0) ph0 += pn;
    else if ((n >> 2) == 1) ph1 += pn;
    else if ((n >> 2) == 2) ph2 += pn;
    else ph3 += pn;
  }

  ph0 += __shfl_xor(ph0, 16); ph0 += __shfl_xor(ph0, 32);
  ph1 += __shfl_xor(ph1, 16); ph1 += __shfl_xor(ph1, 32);
  ph2 += __shfl_xor(ph2, 16); ph2 += __shfl_xor(ph2, 32);
  ph3 += __shfl_xor(ph3, 16); ph3 += __shfl_xor(ph3, 32);

  const float logit = (lg == 0) ? ph0 : (lg == 1) ? ph1
                    : (lg == 2) ? ph2 : ph3;
  elog[(size_t)p * 4 + lg] = expf(logit);
}

// ---------------------------------------------------------------------------
// Aggregation: one wave per dst node, 4 nodes/block; streams CSR bucket.
// ---------------------------------------------------------------------------
__global__ __launch_bounds__(256)
void aggregate(const unsigned short* __restrict__ xlb,
               const float* __restrict__ elog,
               const int* __restrict__ ssrc, const int* __restrict__ row_start,
               const float* __restrict__ bias, float* __restrict__ out) {
  const int wid  = threadIdx.x >> 6;
  const int lane = threadIdx.x & 63;
  const int d    = blockIdx.x * 4 + wid;
  const int h = lane >> 4;
  const int c = lane * 4;
  float ax = 0.f, ay = 0.f, az = 0.f, aw = 0.f;
  float dtot = 0.f;
  const int beg = row_start[d], end = row_start[d + 1];
  for (int p = beg; p < end; ++p) {
    const float ev = elog[(size_t)p * 4 + h];
    const int s = ssrc[p];
    const uint2 xv = *(const uint2*)(xlb + (size_t)s * 256 + c);
    ax += ev * bflo(xv.x); ay += ev * bfhi(xv.x);
    az += ev * bflo(xv.y); aw += ev * bfhi(xv.y);
    dtot += ev;
  }
  const float inv = 1.f / (dtot + 1e-16f);
  const float4 bv = *(const float4*)(bias + c);
  float4 o;
  o.x = bv.x + ax * inv; o.y = bv.y + ay * inv;
  o.z = bv.z + az * inv; o.w = bv.w + aw * inv;
  *(float4*)(out + (size_t)d * 256 + c) = o;
}

extern "C" void kernel_launch(void* const* d_in, const int* in_sizes, int n_in,
                              void* d_out, int out_size, void* d_ws, size_t ws_size,
                              hipStream_t stream) {
  const float* x    = (const float*)d_in[0];
  const int*   ei   = (const int*)d_in[1];
  const float* ea   = (const float*)d_in[2];
  const float* Wl1  = (const float*)d_in[3];
  const float* bl1  = (const float*)d_in[4];
  const float* Wr1  = (const float*)d_in[5];
  const float* br1  = (const float*)d_in[6];
  const float* We1  = (const float*)d_in[7];
  const float* att1 = (const float*)d_in[8];
  const float* bias1= (const float*)d_in[9];
  const float* Wl2  = (const float*)d_in[10];
  const float* bl2  = (const float*)d_in[11];
  const float* Wr2  = (const float*)d_in[12];
  const float* br2  = (const float*)d_in[13];
  const float* We2  = (const float*)d_in[14];
  const float* att2 = (const float*)d_in[15];
  const float* bias2= (const float*)d_in[16];

  float* out = (float*)d_out;
  float* ws  = (float*)d_ws;

  float* elog = ws;                                    // NE*4 f32
  unsigned short* xlb  = (unsigned short*)(elog + (size_t)NE * 4); // NN*256
  unsigned short* xrb  = xlb + (size_t)NN * 256;       // NN*256
  unsigned short* wet1 = xrb + (size_t)NN * 256;       // 16384
  unsigned short* wet2 = wet1 + 16384;                 // 16384
  unsigned short* wlf1 = wet2 + 16384;                 // 128*256 = 32768
  unsigned short* wrf1 = wlf1 + 32768;                 // 32768
  unsigned short* wlf2 = wrf1 + 32768;                 // 256*256 = 65536
  unsigned short* wrf2 = wlf2 + 65536;                 // 65536
  int* cur       = (int*)(wrf2 + 65536);               // NN
  int* row_start = cur + NN;                           // NN+1
  int* eid       = row_start + NN + 1;                 // NE
  int* ssrc      = eid + NE;                           // NE
  int* sdst      = ssrc + NE;                          // NE
  unsigned short* eab = (unsigned short*)(sdst + NE);  // NE*64 bf16 (optional)
  const size_t need_eab =
      ((char*)(eab + (size_t)NE * 64)) - (char*)d_ws;
  const bool use_eab = ws_size >= need_eab;
  float* h1 = out;  // d_out doubles as h1

  const int* src = ei;
  const int* dst = ei + NE;

  const dim3 ggrid((NN + 63) / 64, 2);   // 782 x 2
  const int  egrid = NE / 64;            // 12500
  const int  epb   = (NE + 255) / 256;
  const int  agrid = NN / 4;             // 12500

  // ---- prep: CSR + bf16 weight tables (+ eab) ----
  hipMemsetAsync(cur, 0, NN * sizeof(int), stream);
  conv_wet<<<dim3(64, 2), 256, 0, stream>>>(We1, wet1, We2, wet2);
  conv_wf<<<128, 256, 0, stream>>>(Wl1, wlf1, 128);
  conv_wf<<<128, 256, 0, stream>>>(Wr1, wrf1, 128);
  conv_wf<<<256, 256, 0, stream>>>(Wl2, wlf2, 256);
  conv_wf<<<256, 256, 0, stream>>>(Wr2, wrf2, 256);
  dst_hist<<<epb, 256, 0, stream>>>(dst, cur);
  exscan<<<1, 1024, 0, stream>>>(cur, row_start, cur, NN);
  bucket_fill<<<epb, 256, 0, stream>>>(src, dst, cur, eid, ssrc, sdst);
  if (use_eab)
    conv_eab<<<NE * 16 / 256, 256, 0, stream>>>(ea, eid, eab);

  // ---- layer 1 ----
  gemm_mfma<4><<<ggrid, 256, 0, stream>>>(x, wlf1, bl1, xlb, wrf1, br1, xrb);
  if (use_eab)
    edge_logits_swap<1><<<egrid, 256, 0, stream>>>(ea, eab, wet1, xlb, xrb,
                                                   att1, eid, ssrc, sdst, elog);
  else
    edge_logits_swap<0><<<egrid, 256, 0, stream>>>(ea, eab, wet1, xlb, xrb,
                                                   att1, eid, ssrc, sdst, elog);
  aggregate<<<agrid, 256, 0, stream>>>(xlb, elog, ssrc, row_start, bias1, h1);

  // ---- layer 2 ----
  gemm_mfma<8><<<ggrid, 256, 0, stream>>>(h1, wlf2, bl2, xlb, wrf2, br2, xrb);
  if (use_eab)
    edge_logits_swap<1><<<egrid, 256, 0, stream>>>(ea, eab, wet2, xlb, xrb,
                                                   att2, eid, ssrc, sdst, elog);
  else
    edge_logits_swap<0><<<egrid, 256, 0, stream>>>(ea, eab, wet2, xlb, xrb,
                                                   att2, eid, ssrc, sdst, elog);
  aggregate<<<agrid, 256, 0, stream>>>(xlb, elog, ssrc, row_start, bias2, out);
}